// Round 10
// baseline (959.316 us; speedup 1.0000x reference)
//
#include <hip/hip_runtime.h>
#include <hip/hip_bf16.h>

typedef __hip_bfloat16 bf16;
typedef __attribute__((ext_vector_type(8))) short short8;
typedef __attribute__((ext_vector_type(4))) float f32x4;

static constexpr int N_NODES  = 50000;
static constexpr int N_EDGES  = 800000;
static constexpr int F_IN     = 128;
static constexpr int D_HID    = 128;
static constexpr int H_HEADS  = 3;
static constexpr int F_OUT    = 40;
static constexpr float BN_EPS = 1e-5f;
static constexpr float SLOPE  = 0.2f;

__device__ __forceinline__ float bfLo(unsigned int u) { return __uint_as_float(u << 16); }
__device__ __forceinline__ float bfHi(unsigned int u) { return __uint_as_float(u & 0xffff0000u); }
__device__ __forceinline__ float bfs(unsigned short s) { return __uint_as_float(((unsigned int)s) << 16); }

// ---------------- MFMA GEMM + fused el/er epilogue --------------------------
__global__ __launch_bounds__(256) void gemm_mfma(const short* __restrict__ A,
                                                 const short* __restrict__ WT,
                                                 bf16* __restrict__ C,
                                                 const float* __restrict__ alp,
                                                 const float* __restrict__ arp,
                                                 float* __restrict__ el,
                                                 float* __restrict__ er,
                                                 int M, int K, int Nc, int els, int ers) {
  constexpr int BM = 64, BN = 64, BK = 64, LDP = BK + 8;
  __shared__ short As[BM * LDP];
  __shared__ short Bs[BN * LDP];
  int tid = threadIdx.x;
  int wave = tid >> 6, lane = tid & 63;
  int bm = blockIdx.y, bn = blockIdx.x;
  int lrow = tid >> 3;
  int kcol = (tid & 7) * 8;

  // hoisted staging pointers (advance by BK per K-step)
  int r0 = lrow, r1 = lrow + 32;
  int gr0 = bm * BM + r0; if (gr0 >= M) gr0 = M - 1;
  int gr1 = bm * BM + r1; if (gr1 >= M) gr1 = M - 1;
  const short* ga0 = A + (size_t)gr0 * K + kcol;
  const short* ga1 = A + (size_t)gr1 * K + kcol;
  const short* gb0 = WT + (size_t)(bn * BN + r0) * K + kcol;
  const short* gb1 = WT + (size_t)(bn * BN + r1) * K + kcol;
  short* la0 = &As[r0 * LDP + kcol];
  short* la1 = &As[r1 * LDP + kcol];
  short* lb0 = &Bs[r0 * LDP + kcol];
  short* lb1 = &Bs[r1 * LDP + kcol];

  f32x4 acc[4];
#pragma unroll
  for (int i = 0; i < 4; ++i) acc[i] = (f32x4){0.f, 0.f, 0.f, 0.f};

  int m15 = lane & 15;
  int ksub = (lane >> 4) * 8;
  const short* abase = &As[(wave * 16 + m15) * LDP + ksub];
  const short* bbase0 = &Bs[(0 * 16 + m15) * LDP + ksub];
  const short* bbase1 = &Bs[(1 * 16 + m15) * LDP + ksub];
  const short* bbase2 = &Bs[(2 * 16 + m15) * LDP + ksub];
  const short* bbase3 = &Bs[(3 * 16 + m15) * LDP + ksub];

  for (int k0 = 0; k0 < K; k0 += BK) {
    *(short8*)la0 = *(const short8*)ga0; ga0 += BK;
    *(short8*)la1 = *(const short8*)ga1; ga1 += BK;
    *(short8*)lb0 = *(const short8*)gb0; gb0 += BK;
    *(short8*)lb1 = *(const short8*)gb1; gb1 += BK;
    __syncthreads();
#pragma unroll
    for (int ks = 0; ks < BK; ks += 32) {
      short8 a = *(const short8*)(abase + ks);
      acc[0] = __builtin_amdgcn_mfma_f32_16x16x32_bf16(a, *(const short8*)(bbase0 + ks), acc[0], 0, 0, 0);
      acc[1] = __builtin_amdgcn_mfma_f32_16x16x32_bf16(a, *(const short8*)(bbase1 + ks), acc[1], 0, 0, 0);
      acc[2] = __builtin_amdgcn_mfma_f32_16x16x32_bf16(a, *(const short8*)(bbase2 + ks), acc[2], 0, 0, 0);
      acc[3] = __builtin_amdgcn_mfma_f32_16x16x32_bf16(a, *(const short8*)(bbase3 + ks), acc[3], 0, 0, 0);
    }
    __syncthreads();
  }

  int h = (bn * 64) >> 7;
  float alv[4], arv[4];
#pragma unroll
  for (int nb = 0; nb < 4; ++nb) {
    int col = bn * BN + nb * 16 + m15;
    alv[nb] = alp[col];
    arv[nb] = arp[col];
  }
#pragma unroll
  for (int r = 0; r < 4; ++r) {
    int row = bm * BM + wave * 16 + (lane >> 4) * 4 + r;
    float pe = 0.f, pr = 0.f;
#pragma unroll
    for (int nb = 0; nb < 4; ++nb) {
      float v = acc[nb][r];
      pe += v * alv[nb];
      pr += v * arv[nb];
      int col = bn * BN + nb * 16 + m15;
      if (row < M && col < Nc)
        C[(size_t)row * Nc + col] = __float2bfloat16(v);
    }
#pragma unroll
    for (int off = 1; off < 16; off <<= 1) {
      pe += __shfl_xor(pe, off);
      pr += __shfl_xor(pr, off);
    }
    if (m15 == 0 && row < M) {
      atomicAdd(&el[(size_t)row * els + h], pe);
      atomicAdd(&er[(size_t)row * ers + h], pr);
    }
  }
}

// ------------- prep: cast x, build WT0/1/2, pad al2/ar2, zero cnt/el/er -----
__global__ void prep_kernel(const float* __restrict__ x, bf16* __restrict__ abuf,
                            const float* __restrict__ W0, const float* __restrict__ W1,
                            const float* __restrict__ W2, bf16* __restrict__ WT0,
                            bf16* __restrict__ WT1, bf16* __restrict__ WT2,
                            const float* __restrict__ al2, const float* __restrict__ ar2,
                            float* __restrict__ alp2, float* __restrict__ arp2,
                            int* __restrict__ cnt, float* __restrict__ elbuf,
                            float* __restrict__ er) {
  const int NTOT = N_NODES * F_IN;  // 6.4M
  for (int i = blockIdx.x * blockDim.x + threadIdx.x; i < NTOT;
       i += gridDim.x * blockDim.x) {
    abuf[i] = __float2bfloat16(x[i]);
    if (i < 384 * 384) { int n = i / 384, k = i - n * 384; WT1[i] = __float2bfloat16(W1[(size_t)k * 384 + n]); }
    if (i < 384 * 128) { int n = i / 128, k = i - n * 128; WT0[i] = __float2bfloat16(W0[(size_t)k * 384 + n]); }
    if (i < 64 * 384)  { int n = i / 384, k = i - n * 384; WT2[i] = __float2bfloat16(n < F_OUT ? W2[(size_t)k * F_OUT + n] : 0.f); }
    if (i < 2 * N_NODES) cnt[i] = 0;
    if (i < 4 * N_NODES) elbuf[i] = 0.f;
    if (i < 3 * N_NODES) er[i] = 0.f;
    if (i < 64) { alp2[i] = i < F_OUT ? al2[i] : 0.f; arp2[i] = i < F_OUT ? ar2[i] : 0.f; }
  }
}

// ------------- CSR build ----------------------------------------------------
__global__ void hist_kernel(const int* __restrict__ dst, int* __restrict__ cnt, int E) {
  int i = blockIdx.x * blockDim.x + threadIdx.x;
  if (i < E) atomicAdd(cnt + dst[i], 1);
}

__global__ __launch_bounds__(1024) void scan_kernel(const int* __restrict__ cnt,
                                                    int* __restrict__ row_ptr, int N, int E) {
  __shared__ int part[1024];
  int t = threadIdx.x;
  int chunk = (N + 1023) / 1024;
  int b = t * chunk, e = min(b + chunk, N);
  int s = 0;
  for (int i = b; i < e; ++i) s += cnt[i];
  part[t] = s;
  __syncthreads();
  for (int off = 1; off < 1024; off <<= 1) {
    int v = (t >= off) ? part[t - off] : 0;
    __syncthreads();
    part[t] += v;
    __syncthreads();
  }
  int run = (t == 0) ? 0 : part[t - 1];
  for (int i = b; i < e; ++i) { row_ptr[i] = run; run += cnt[i]; }
  if (t == 1023) row_ptr[N] = E;
}

__global__ void scatter_kernel(const int* __restrict__ src, const int* __restrict__ dst,
                               const int* __restrict__ row_ptr, int* __restrict__ fill,
                               int* __restrict__ csr_src, int E) {
  int i = blockIdx.x * blockDim.x + threadIdx.x;
  if (i < E) {
    int d = dst[i];
    int pos = row_ptr[d] + atomicAdd(fill + d, 1);
    csr_src[pos] = src[i];
  }
}

// ------------- head-split aggregation: wave per dst, ONE head per dispatch --
// Gathers a 12.8 MB slice (word lane of head h) -> better L2 residency.
// Writes bf16-packed output slice. Block 0 (h==0 dispatch) zeroes bnbuf.
__global__ __launch_bounds__(256) void aggr_head_kernel(
    const int* __restrict__ row_ptr, const int* __restrict__ csr_src,
    const float* __restrict__ el4, const float* __restrict__ er,
    const bf16* __restrict__ f, unsigned int* __restrict__ outw,
    float* __restrict__ bnzero, int h, int N) {
  if (bnzero && blockIdx.x == 0) {
    for (int j = threadIdx.x; j < 2 * H_HEADS * D_HID; j += 256) bnzero[j] = 0.f;
  }
  constexpr int W = H_HEADS * D_HID / 2;  // 192 words per row
  int d = (blockIdx.x * 256 + threadIdx.x) >> 6;
  int lane = threadIdx.x & 63;
  if (d >= N) return;
  int beg = row_ptr[d], end = row_ptr[d + 1];
  const unsigned int* fu = (const unsigned int*)f;
  int hoff = h * 64;
  float erd = er[d * H_HEADS + h];
  float a0 = 0.f, a1 = 0.f, sp = 0.f;
  for (int k0 = beg; k0 < end; k0 += 64) {
    int nk = end - k0; if (nk > 64) nk = 64;
    int s_l = 0; float w_l = 0.f;
    if (lane < nk) {
      s_l = csr_src[k0 + lane];
      float sc = el4[(s_l << 2) + h] + erd;
      sc = sc > 0.f ? sc : SLOPE * sc;
      w_l = __expf(sc);
      sp += w_l;
    }
    for (int e = 0; e < nk; ++e) {
      int se = __shfl(s_l, e);
      float w = __shfl(w_l, e);
      unsigned int u = fu[(size_t)se * W + hoff + lane];
      a0 += w * bfLo(u);
      a1 += w * bfHi(u);
    }
  }
#pragma unroll
  for (int off = 32; off > 0; off >>= 1) sp += __shfl_xor(sp, off);
  float inv = 1.f / sp;
  union { bf16 hh[2]; unsigned int u; } pk;
  pk.hh[0] = __float2bfloat16(a0 * inv);
  pk.hh[1] = __float2bfloat16(a1 * inv);
  outw[(size_t)d * W + hoff + lane] = pk.u;
}

// ------------- output-layer aggregation: H=1, D=40, bias fused --------------
__global__ __launch_bounds__(256) void aggr_out_kernel(
    const int* __restrict__ row_ptr, const int* __restrict__ csr_src,
    const float* __restrict__ el, const float* __restrict__ er,
    const bf16* __restrict__ f, const float* __restrict__ bias,
    float* __restrict__ out, int N) {
  constexpr int DW = F_OUT / 2;  // 20 words
  int d = (blockIdx.x * 256 + threadIdx.x) >> 6;
  int lane = threadIdx.x & 63;
  if (d >= N) return;
  int beg = row_ptr[d], end = row_ptr[d + 1];
  const unsigned int* fu = (const unsigned int*)f;
  float erd = er[d];
  float a0 = 0.f, a1 = 0.f, sp = 0.f;
  for (int k0 = beg; k0 < end; k0 += 64) {
    int nk = end - k0; if (nk > 64) nk = 64;
    int s_l = 0; float w_l = 0.f;
    if (lane < nk) {
      s_l = csr_src[k0 + lane];
      float sc = el[s_l] + erd;
      sc = sc > 0.f ? sc : SLOPE * sc;
      w_l = __expf(sc);
      sp += w_l;
    }
    for (int e = 0; e < nk; ++e) {
      int se = __shfl(s_l, e);
      float w = __shfl(w_l, e);
      if (lane < DW) {
        unsigned int u = fu[(size_t)se * DW + lane];
        a0 += w * bfLo(u);
        a1 += w * bfHi(u);
      }
    }
  }
#pragma unroll
  for (int off = 32; off > 0; off >>= 1) sp += __shfl_xor(sp, off);
  if (lane < DW) {
    float inv = 1.f / sp;
    *(float2*)&out[(size_t)d * F_OUT + 2 * lane] =
        make_float2(a0 * inv + bias[2 * lane], a1 * inv + bias[2 * lane + 1]);
  }
}

// ------------- BN stats (bf16 input) ----------------------------------------
__global__ void bn_stats_kernel(const unsigned short* __restrict__ h, float* __restrict__ sum,
                                float* __restrict__ sumsq, int N, int C) {
  int c = threadIdx.x;
  float s = 0.f, s2 = 0.f;
  for (int n = blockIdx.x; n < N; n += gridDim.x) {
    float v = bfs(h[(size_t)n * C + c]);
    s += v; s2 += v * v;
  }
  atomicAdd(sum + c, s);
  atomicAdd(sumsq + c, s2);
}

// ------------- BN apply + ReLU (bf16 in) -> bf16; zero el/er ----------------
__global__ void bn_apply_kernel(const unsigned short* __restrict__ h, const float* __restrict__ sum,
                                const float* __restrict__ sumsq, const float* __restrict__ g,
                                const float* __restrict__ be, bf16* __restrict__ out,
                                float* __restrict__ elz, float* __restrict__ erz,
                                int N, int C) {
  int i = blockIdx.x * blockDim.x + threadIdx.x;
  if (i < 4 * N) elz[i] = 0.f;
  if (i < 3 * N) erz[i] = 0.f;
  if (i >= N * C) return;
  int c = i % C;
  float inv_n = 1.f / (float)N;
  float mu = sum[c] * inv_n;
  float var = sumsq[c] * inv_n - mu * mu;
  float v = (bfs(h[i]) - mu) * rsqrtf(var + BN_EPS) * g[c] + be[c];
  out[i] = __float2bfloat16(v > 0.f ? v : 0.f);
}

static inline int cdiv(int a, int b) { return (a + b - 1) / b; }

extern "C" void kernel_launch(void* const* d_in, const int* in_sizes, int n_in,
                              void* d_out, int out_size, void* d_ws, size_t ws_size,
                              hipStream_t stream) {
  const float* x   = (const float*)d_in[0];
  const int* src   = (const int*)d_in[1];
  const int* dst   = (const int*)d_in[2];
  const float* W0  = (const float*)d_in[3];
  const float* al0 = (const float*)d_in[4];
  const float* ar0 = (const float*)d_in[5];
  const float* W1  = (const float*)d_in[7];
  const float* al1 = (const float*)d_in[8];
  const float* ar1 = (const float*)d_in[9];
  const float* W2  = (const float*)d_in[11];
  const float* al2 = (const float*)d_in[12];
  const float* ar2 = (const float*)d_in[13];
  const float* b2  = (const float*)d_in[14];
  const float* g0  = (const float*)d_in[15];
  const float* be0 = (const float*)d_in[16];
  const float* g1  = (const float*)d_in[17];
  const float* be1 = (const float*)d_in[18];
  float* out = (float*)d_out;

  const int N = N_NODES, E = N_EDGES, H = H_HEADS;
  const int C = H * D_HID;  // 384

  // ---- workspace carve ----
  char* p = (char*)d_ws;
  auto take = [&](size_t bytes) {
    char* r = p;
    p += (bytes + 255) & ~(size_t)255;
    return r;
  };
  bf16*   f_buf   = (bf16*) take((size_t)N * C * sizeof(bf16));
  bf16*   hbuf    = (bf16*) take((size_t)N * C * sizeof(bf16));   // aggregated (bf16 now)
  bf16*   abuf    = (bf16*) take((size_t)N * C * sizeof(bf16));
  float*  elbuf   = (float*)take((size_t)N * 4 * sizeof(float));
  float*  er      = (float*)take((size_t)N * H * sizeof(float));
  float*  bnbuf   = (float*)take((size_t)2 * C * sizeof(float));  // sum | sumsq
  bf16*   WT0     = (bf16*) take((size_t)C * F_IN * sizeof(bf16));
  bf16*   WT1     = (bf16*) take((size_t)C * C * sizeof(bf16));
  bf16*   WT2     = (bf16*) take((size_t)64 * C * sizeof(bf16));
  float*  alp2    = (float*)take(64 * sizeof(float));
  float*  arp2    = (float*)take(64 * sizeof(float));
  int*    cnt     = (int*)take((size_t)2 * N * sizeof(int));      // hist | fill
  int*    row_ptr = (int*)take((size_t)(N + 1) * sizeof(int));
  int*    csr_src = (int*)take((size_t)E * sizeof(int));
  float*  bnsum = bnbuf, *bnsq = bnbuf + C;
  int*    fill  = cnt + N;

  // ---- prep + CSR build ----
  prep_kernel<<<cdiv(N * F_IN, 256), 256, 0, stream>>>(x, abuf, W0, W1, W2, WT0, WT1, WT2,
                                                       al2, ar2, alp2, arp2, cnt, elbuf, er);
  hist_kernel<<<cdiv(E, 256), 256, 0, stream>>>(dst, cnt, E);
  scan_kernel<<<1, 1024, 0, stream>>>(cnt, row_ptr, N, E);
  scatter_kernel<<<cdiv(E, 256), 256, 0, stream>>>(src, dst, row_ptr, fill, csr_src, E);

  // ================= layer 0 =================
  gemm_mfma<<<dim3(C / 64, cdiv(N, 64)), 256, 0, stream>>>(
      (const short*)abuf, (const short*)WT0, f_buf, al0, ar0, elbuf, er, N, F_IN, C, 4, 3);
  for (int h = 0; h < H; ++h)
    aggr_head_kernel<<<cdiv(N * 64, 256), 256, 0, stream>>>(
        row_ptr, csr_src, elbuf, er, f_buf, (unsigned int*)hbuf,
        h == 0 ? bnbuf : nullptr, h, N);
  bn_stats_kernel<<<256, C, 0, stream>>>((const unsigned short*)hbuf, bnsum, bnsq, N, C);
  bn_apply_kernel<<<cdiv(N * C, 256), 256, 0, stream>>>((const unsigned short*)hbuf, bnsum, bnsq,
                                                        g0, be0, abuf, elbuf, er, N, C);

  // ================= layer 1 =================
  gemm_mfma<<<dim3(C / 64, cdiv(N, 64)), 256, 0, stream>>>(
      (const short*)abuf, (const short*)WT1, f_buf, al1, ar1, elbuf, er, N, C, C, 4, 3);
  for (int h = 0; h < H; ++h)
    aggr_head_kernel<<<cdiv(N * 64, 256), 256, 0, stream>>>(
        row_ptr, csr_src, elbuf, er, f_buf, (unsigned int*)hbuf,
        h == 0 ? bnbuf : nullptr, h, N);
  bn_stats_kernel<<<256, C, 0, stream>>>((const unsigned short*)hbuf, bnsum, bnsq, N, C);
  bn_apply_kernel<<<cdiv(N * C, 256), 256, 0, stream>>>((const unsigned short*)hbuf, bnsum, bnsq,
                                                        g1, be1, abuf, elbuf, er, N, C);

  // ================= layer 2 (H=1, D=40, bias fused, direct to out) =========
  gemm_mfma<<<dim3(1, cdiv(N, 64)), 256, 0, stream>>>(
      (const short*)abuf, (const short*)WT2, f_buf, alp2, arp2, elbuf, er, N, C, F_OUT, 1, 1);
  aggr_out_kernel<<<cdiv(N * 64, 256), 256, 0, stream>>>(
      row_ptr, csr_src, elbuf, er, f_buf, b2, out, N);
}

// Round 11
// 732.269 us; speedup vs baseline: 1.3101x; 1.3101x over previous
//
#include <hip/hip_runtime.h>
#include <hip/hip_bf16.h>

typedef __hip_bfloat16 bf16;
typedef __attribute__((ext_vector_type(8))) short short8;
typedef __attribute__((ext_vector_type(4))) float f32x4;

static constexpr int N_NODES  = 50000;
static constexpr int N_EDGES  = 800000;
static constexpr int F_IN     = 128;
static constexpr int D_HID    = 128;
static constexpr int H_HEADS  = 3;
static constexpr int F_OUT    = 40;
static constexpr float BN_EPS = 1e-5f;
static constexpr float SLOPE  = 0.2f;

__device__ __forceinline__ float bfLo(unsigned int u) { return __uint_as_float(u << 16); }
__device__ __forceinline__ float bfHi(unsigned int u) { return __uint_as_float(u & 0xffff0000u); }
__device__ __forceinline__ float bfs(unsigned short s) { return __uint_as_float(((unsigned int)s) << 16); }

// ---------------- MFMA GEMM + fused el/er epilogue --------------------------
__global__ __launch_bounds__(256) void gemm_mfma(const short* __restrict__ A,
                                                 const short* __restrict__ WT,
                                                 bf16* __restrict__ C,
                                                 const float* __restrict__ alp,
                                                 const float* __restrict__ arp,
                                                 float* __restrict__ el,
                                                 float* __restrict__ er,
                                                 int M, int K, int Nc, int els, int ers) {
  constexpr int BM = 64, BN = 64, BK = 64, LDP = BK + 8;
  __shared__ short As[BM * LDP];
  __shared__ short Bs[BN * LDP];
  int tid = threadIdx.x;
  int wave = tid >> 6, lane = tid & 63;
  int bm = blockIdx.y, bn = blockIdx.x;
  int lrow = tid >> 3;
  int kcol = (tid & 7) * 8;

  int r0 = lrow, r1 = lrow + 32;
  int gr0 = bm * BM + r0; if (gr0 >= M) gr0 = M - 1;
  int gr1 = bm * BM + r1; if (gr1 >= M) gr1 = M - 1;
  const short* ga0 = A + (size_t)gr0 * K + kcol;
  const short* ga1 = A + (size_t)gr1 * K + kcol;
  const short* gb0 = WT + (size_t)(bn * BN + r0) * K + kcol;
  const short* gb1 = WT + (size_t)(bn * BN + r1) * K + kcol;
  short* la0 = &As[r0 * LDP + kcol];
  short* la1 = &As[r1 * LDP + kcol];
  short* lb0 = &Bs[r0 * LDP + kcol];
  short* lb1 = &Bs[r1 * LDP + kcol];

  f32x4 acc[4];
#pragma unroll
  for (int i = 0; i < 4; ++i) acc[i] = (f32x4){0.f, 0.f, 0.f, 0.f};

  int m15 = lane & 15;
  int ksub = (lane >> 4) * 8;
  const short* abase = &As[(wave * 16 + m15) * LDP + ksub];
  const short* bbase0 = &Bs[(0 * 16 + m15) * LDP + ksub];
  const short* bbase1 = &Bs[(1 * 16 + m15) * LDP + ksub];
  const short* bbase2 = &Bs[(2 * 16 + m15) * LDP + ksub];
  const short* bbase3 = &Bs[(3 * 16 + m15) * LDP + ksub];

  for (int k0 = 0; k0 < K; k0 += BK) {
    *(short8*)la0 = *(const short8*)ga0; ga0 += BK;
    *(short8*)la1 = *(const short8*)ga1; ga1 += BK;
    *(short8*)lb0 = *(const short8*)gb0; gb0 += BK;
    *(short8*)lb1 = *(const short8*)gb1; gb1 += BK;
    __syncthreads();
#pragma unroll
    for (int ks = 0; ks < BK; ks += 32) {
      short8 a = *(const short8*)(abase + ks);
      acc[0] = __builtin_amdgcn_mfma_f32_16x16x32_bf16(a, *(const short8*)(bbase0 + ks), acc[0], 0, 0, 0);
      acc[1] = __builtin_amdgcn_mfma_f32_16x16x32_bf16(a, *(const short8*)(bbase1 + ks), acc[1], 0, 0, 0);
      acc[2] = __builtin_amdgcn_mfma_f32_16x16x32_bf16(a, *(const short8*)(bbase2 + ks), acc[2], 0, 0, 0);
      acc[3] = __builtin_amdgcn_mfma_f32_16x16x32_bf16(a, *(const short8*)(bbase3 + ks), acc[3], 0, 0, 0);
    }
    __syncthreads();
  }

  int h = (bn * 64) >> 7;
  float alv[4], arv[4];
#pragma unroll
  for (int nb = 0; nb < 4; ++nb) {
    int col = bn * BN + nb * 16 + m15;
    alv[nb] = alp[col];
    arv[nb] = arp[col];
  }
#pragma unroll
  for (int r = 0; r < 4; ++r) {
    int row = bm * BM + wave * 16 + (lane >> 4) * 4 + r;
    float pe = 0.f, pr = 0.f;
#pragma unroll
    for (int nb = 0; nb < 4; ++nb) {
      float v = acc[nb][r];
      pe += v * alv[nb];
      pr += v * arv[nb];
      int col = bn * BN + nb * 16 + m15;
      if (row < M && col < Nc)
        C[(size_t)row * Nc + col] = __float2bfloat16(v);
    }
#pragma unroll
    for (int off = 1; off < 16; off <<= 1) {
      pe += __shfl_xor(pe, off);
      pr += __shfl_xor(pr, off);
    }
    if (m15 == 0 && row < M) {
      atomicAdd(&el[(size_t)row * els + h], pe);
      atomicAdd(&er[(size_t)row * ers + h], pr);
    }
  }
}

// ------------- prep: cast x, build WT0/1/2, pad al2/ar2, zero cnt/el/er -----
__global__ void prep_kernel(const float* __restrict__ x, bf16* __restrict__ abuf,
                            const float* __restrict__ W0, const float* __restrict__ W1,
                            const float* __restrict__ W2, bf16* __restrict__ WT0,
                            bf16* __restrict__ WT1, bf16* __restrict__ WT2,
                            const float* __restrict__ al2, const float* __restrict__ ar2,
                            float* __restrict__ alp2, float* __restrict__ arp2,
                            int* __restrict__ cnt, float* __restrict__ elbuf,
                            float* __restrict__ er) {
  const int NTOT = N_NODES * F_IN;  // 6.4M
  for (int i = blockIdx.x * blockDim.x + threadIdx.x; i < NTOT;
       i += gridDim.x * blockDim.x) {
    abuf[i] = __float2bfloat16(x[i]);
    if (i < 384 * 384) { int n = i / 384, k = i - n * 384; WT1[i] = __float2bfloat16(W1[(size_t)k * 384 + n]); }
    if (i < 384 * 128) { int n = i / 128, k = i - n * 128; WT0[i] = __float2bfloat16(W0[(size_t)k * 384 + n]); }
    if (i < 64 * 384)  { int n = i / 384, k = i - n * 384; WT2[i] = __float2bfloat16(n < F_OUT ? W2[(size_t)k * F_OUT + n] : 0.f); }
    if (i < 2 * N_NODES) cnt[i] = 0;
    if (i < 4 * N_NODES) elbuf[i] = 0.f;
    if (i < 3 * N_NODES) er[i] = 0.f;
    if (i < 64) { alp2[i] = i < F_OUT ? al2[i] : 0.f; arp2[i] = i < F_OUT ? ar2[i] : 0.f; }
  }
}

// ------------- CSR build ----------------------------------------------------
__global__ void hist_kernel(const int* __restrict__ dst, int* __restrict__ cnt, int E) {
  int i = blockIdx.x * blockDim.x + threadIdx.x;
  if (i < E) atomicAdd(cnt + dst[i], 1);
}

// 3-phase parallel exclusive scan of cnt[N] -> row_ptr[N+1]
__global__ void scan_part_kernel(const int* __restrict__ cnt, int* __restrict__ blksum, int N) {
  __shared__ int sh[256];
  int i = blockIdx.x * 256 + threadIdx.x;
  sh[threadIdx.x] = (i < N) ? cnt[i] : 0;
  __syncthreads();
  for (int off = 128; off > 0; off >>= 1) {
    if (threadIdx.x < off) sh[threadIdx.x] += sh[threadIdx.x + off];
    __syncthreads();
  }
  if (threadIdx.x == 0) blksum[blockIdx.x] = sh[0];
}

__global__ void scan_top_kernel(const int* __restrict__ blksum, int* __restrict__ blkoff, int nblk) {
  __shared__ int sh[256];
  int t = threadIdx.x;
  int v = (t < nblk) ? blksum[t] : 0;
  sh[t] = v;
  __syncthreads();
  for (int off = 1; off < 256; off <<= 1) {
    int u = (t >= off) ? sh[t - off] : 0;
    __syncthreads();
    sh[t] += u;
    __syncthreads();
  }
  if (t < nblk) blkoff[t] = sh[t] - v;  // exclusive
}

__global__ void scan_write_kernel(const int* __restrict__ cnt, const int* __restrict__ blkoff,
                                  int* __restrict__ row_ptr, int N, int E) {
  __shared__ int sh[256];
  int i = blockIdx.x * 256 + threadIdx.x;
  int t = threadIdx.x;
  int v = (i < N) ? cnt[i] : 0;
  sh[t] = v;
  __syncthreads();
  for (int off = 1; off < 256; off <<= 1) {
    int u = (t >= off) ? sh[t - off] : 0;
    __syncthreads();
    sh[t] += u;
    __syncthreads();
  }
  if (i < N) row_ptr[i] = blkoff[blockIdx.x] + sh[t] - v;
  if (i == 0) row_ptr[N] = E;
}

__global__ void scatter_kernel(const int* __restrict__ src, const int* __restrict__ dst,
                               const int* __restrict__ row_ptr, int* __restrict__ fill,
                               int* __restrict__ csr_src, int E) {
  int i = blockIdx.x * blockDim.x + threadIdx.x;
  if (i < E) {
    int d = dst[i];
    int pos = row_ptr[d] + atomicAdd(fill + d, 1);
    csr_src[pos] = src[i];
  }
}

// ------------- fused aggregation: wave per dst, 3 heads, no-max softmax -----
// Lane-batched weights + shuffle broadcast; bf16-packed output.
template <int H, int D>
__global__ __launch_bounds__(256) void aggr_fused_kernel(
    const int* __restrict__ row_ptr, const int* __restrict__ csr_src,
    const float4* __restrict__ el4, const float* __restrict__ er,
    const bf16* __restrict__ f, unsigned int* __restrict__ outw,
    float* __restrict__ bnzero, int N) {
  if (blockIdx.x == 0) {
    for (int j = threadIdx.x; j < 2 * H * D; j += 256) bnzero[j] = 0.f;
  }
  constexpr int W = H * D / 2;   // words per row (192)
  constexpr int J = W / 64;      // words per lane (3) == H
  int d = (blockIdx.x * 256 + threadIdx.x) >> 6;
  int lane = threadIdx.x & 63;
  if (d >= N) return;
  int beg = row_ptr[d], end = row_ptr[d + 1];
  const unsigned int* fu = (const unsigned int*)f;

  float erd[H];
#pragma unroll
  for (int h = 0; h < H; ++h) erd[h] = er[d * H + h];
  float acc[J][2];
#pragma unroll
  for (int j = 0; j < J; ++j) acc[j][0] = acc[j][1] = 0.f;
  float sp[H];
#pragma unroll
  for (int h = 0; h < H; ++h) sp[h] = 0.f;

  for (int k0 = beg; k0 < end; k0 += 64) {
    int nk = end - k0; if (nk > 64) nk = 64;
    int s_l = 0;
    float w_l[H];
#pragma unroll
    for (int h = 0; h < H; ++h) w_l[h] = 0.f;
    if (lane < nk) {
      s_l = csr_src[k0 + lane];
      float4 e4 = el4[s_l];
      float ev[3] = {e4.x, e4.y, e4.z};
#pragma unroll
      for (int h = 0; h < H; ++h) {
        float sc = ev[h] + erd[h];
        sc = sc > 0.f ? sc : SLOPE * sc;
        float w = __expf(sc);
        w_l[h] = w;
        sp[h] += w;
      }
    }
    for (int e = 0; e < nk; ++e) {
      int se = __shfl(s_l, e);
      float wh[H];
#pragma unroll
      for (int h = 0; h < H; ++h) wh[h] = __shfl(w_l[h], e);
      size_t b = (size_t)se * W;
#pragma unroll
      for (int j = 0; j < J; ++j) {
        unsigned int u = fu[b + 64 * j + lane];
        acc[j][0] += wh[j] * bfLo(u);
        acc[j][1] += wh[j] * bfHi(u);
      }
    }
  }
#pragma unroll
  for (int h = 0; h < H; ++h) {
#pragma unroll
    for (int off = 32; off > 0; off >>= 1) sp[h] += __shfl_xor(sp[h], off);
  }
#pragma unroll
  for (int j = 0; j < J; ++j) {
    float inv = 1.f / sp[j];
    union { bf16 hh[2]; unsigned int u; } pk;
    pk.hh[0] = __float2bfloat16(acc[j][0] * inv);
    pk.hh[1] = __float2bfloat16(acc[j][1] * inv);
    outw[(size_t)d * W + 64 * j + lane] = pk.u;
  }
}

// ------------- output-layer aggregation: H=1, D=40, bias fused --------------
__global__ __launch_bounds__(256) void aggr_out_kernel(
    const int* __restrict__ row_ptr, const int* __restrict__ csr_src,
    const float* __restrict__ el, const float* __restrict__ er,
    const bf16* __restrict__ f, const float* __restrict__ bias,
    float* __restrict__ out, int N) {
  constexpr int DW = F_OUT / 2;  // 20 words
  int d = (blockIdx.x * 256 + threadIdx.x) >> 6;
  int lane = threadIdx.x & 63;
  if (d >= N) return;
  int beg = row_ptr[d], end = row_ptr[d + 1];
  const unsigned int* fu = (const unsigned int*)f;
  float erd = er[d];
  float a0 = 0.f, a1 = 0.f, sp = 0.f;
  for (int k0 = beg; k0 < end; k0 += 64) {
    int nk = end - k0; if (nk > 64) nk = 64;
    int s_l = 0; float w_l = 0.f;
    if (lane < nk) {
      s_l = csr_src[k0 + lane];
      float sc = el[s_l] + erd;
      sc = sc > 0.f ? sc : SLOPE * sc;
      w_l = __expf(sc);
      sp += w_l;
    }
    for (int e = 0; e < nk; ++e) {
      int se = __shfl(s_l, e);
      float w = __shfl(w_l, e);
      if (lane < DW) {
        unsigned int u = fu[(size_t)se * DW + lane];
        a0 += w * bfLo(u);
        a1 += w * bfHi(u);
      }
    }
  }
#pragma unroll
  for (int off = 32; off > 0; off >>= 1) sp += __shfl_xor(sp, off);
  if (lane < DW) {
    float inv = 1.f / sp;
    *(float2*)&out[(size_t)d * F_OUT + 2 * lane] =
        make_float2(a0 * inv + bias[2 * lane], a1 * inv + bias[2 * lane + 1]);
  }
}

// ------------- BN stats (bf16 input) ----------------------------------------
__global__ void bn_stats_kernel(const unsigned short* __restrict__ h, float* __restrict__ sum,
                                float* __restrict__ sumsq, int N, int C) {
  int c = threadIdx.x;
  float s = 0.f, s2 = 0.f;
  for (int n = blockIdx.x; n < N; n += gridDim.x) {
    float v = bfs(h[(size_t)n * C + c]);
    s += v; s2 += v * v;
  }
  atomicAdd(sum + c, s);
  atomicAdd(sumsq + c, s2);
}

// ------------- BN apply + ReLU (bf16 in) -> bf16; zero el/er ----------------
__global__ void bn_apply_kernel(const unsigned short* __restrict__ h, const float* __restrict__ sum,
                                const float* __restrict__ sumsq, const float* __restrict__ g,
                                const float* __restrict__ be, bf16* __restrict__ out,
                                float* __restrict__ elz, float* __restrict__ erz,
                                int N, int C) {
  int i = blockIdx.x * blockDim.x + threadIdx.x;
  if (i < 4 * N) elz[i] = 0.f;
  if (i < 3 * N) erz[i] = 0.f;
  if (i >= N * C) return;
  int c = i % C;
  float inv_n = 1.f / (float)N;
  float mu = sum[c] * inv_n;
  float var = sumsq[c] * inv_n - mu * mu;
  float v = (bfs(h[i]) - mu) * rsqrtf(var + BN_EPS) * g[c] + be[c];
  out[i] = __float2bfloat16(v > 0.f ? v : 0.f);
}

static inline int cdiv(int a, int b) { return (a + b - 1) / b; }

extern "C" void kernel_launch(void* const* d_in, const int* in_sizes, int n_in,
                              void* d_out, int out_size, void* d_ws, size_t ws_size,
                              hipStream_t stream) {
  const float* x   = (const float*)d_in[0];
  const int* src   = (const int*)d_in[1];
  const int* dst   = (const int*)d_in[2];
  const float* W0  = (const float*)d_in[3];
  const float* al0 = (const float*)d_in[4];
  const float* ar0 = (const float*)d_in[5];
  const float* W1  = (const float*)d_in[7];
  const float* al1 = (const float*)d_in[8];
  const float* ar1 = (const float*)d_in[9];
  const float* W2  = (const float*)d_in[11];
  const float* al2 = (const float*)d_in[12];
  const float* ar2 = (const float*)d_in[13];
  const float* b2  = (const float*)d_in[14];
  const float* g0  = (const float*)d_in[15];
  const float* be0 = (const float*)d_in[16];
  const float* g1  = (const float*)d_in[17];
  const float* be1 = (const float*)d_in[18];
  float* out = (float*)d_out;

  const int N = N_NODES, E = N_EDGES, H = H_HEADS;
  const int C = H * D_HID;  // 384
  const int nblk = cdiv(N, 256);  // 196

  // ---- workspace carve ----
  char* p = (char*)d_ws;
  auto take = [&](size_t bytes) {
    char* r = p;
    p += (bytes + 255) & ~(size_t)255;
    return r;
  };
  bf16*   f_buf   = (bf16*) take((size_t)N * C * sizeof(bf16));
  bf16*   hbuf    = (bf16*) take((size_t)N * C * sizeof(bf16));
  bf16*   abuf    = (bf16*) take((size_t)N * C * sizeof(bf16));
  float*  elbuf   = (float*)take((size_t)N * 4 * sizeof(float));
  float*  er      = (float*)take((size_t)N * H * sizeof(float));
  float*  bnbuf   = (float*)take((size_t)2 * C * sizeof(float));  // sum | sumsq
  bf16*   WT0     = (bf16*) take((size_t)C * F_IN * sizeof(bf16));
  bf16*   WT1     = (bf16*) take((size_t)C * C * sizeof(bf16));
  bf16*   WT2     = (bf16*) take((size_t)64 * C * sizeof(bf16));
  float*  alp2    = (float*)take(64 * sizeof(float));
  float*  arp2    = (float*)take(64 * sizeof(float));
  int*    cnt     = (int*)take((size_t)2 * N * sizeof(int));      // hist | fill
  int*    row_ptr = (int*)take((size_t)(N + 1) * sizeof(int));
  int*    csr_src = (int*)take((size_t)E * sizeof(int));
  int*    blksum  = (int*)take(256 * sizeof(int));
  int*    blkoff  = (int*)take(256 * sizeof(int));
  float*  bnsum = bnbuf, *bnsq = bnbuf + C;
  int*    fill  = cnt + N;

  // ---- prep + CSR build ----
  prep_kernel<<<cdiv(N * F_IN, 256), 256, 0, stream>>>(x, abuf, W0, W1, W2, WT0, WT1, WT2,
                                                       al2, ar2, alp2, arp2, cnt, elbuf, er);
  hist_kernel<<<cdiv(E, 256), 256, 0, stream>>>(dst, cnt, E);
  scan_part_kernel<<<nblk, 256, 0, stream>>>(cnt, blksum, N);
  scan_top_kernel<<<1, 256, 0, stream>>>(blksum, blkoff, nblk);
  scan_write_kernel<<<nblk, 256, 0, stream>>>(cnt, blkoff, row_ptr, N, E);
  scatter_kernel<<<cdiv(E, 256), 256, 0, stream>>>(src, dst, row_ptr, fill, csr_src, E);

  // ================= layer 0 =================
  gemm_mfma<<<dim3(C / 64, cdiv(N, 64)), 256, 0, stream>>>(
      (const short*)abuf, (const short*)WT0, f_buf, al0, ar0, elbuf, er, N, F_IN, C, 4, 3);
  aggr_fused_kernel<H_HEADS, D_HID><<<cdiv(N * 64, 256), 256, 0, stream>>>(
      row_ptr, csr_src, (const float4*)elbuf, er, f_buf, (unsigned int*)hbuf, bnbuf, N);
  bn_stats_kernel<<<256, C, 0, stream>>>((const unsigned short*)hbuf, bnsum, bnsq, N, C);
  bn_apply_kernel<<<cdiv(N * C, 256), 256, 0, stream>>>((const unsigned short*)hbuf, bnsum, bnsq,
                                                        g0, be0, abuf, elbuf, er, N, C);

  // ================= layer 1 =================
  gemm_mfma<<<dim3(C / 64, cdiv(N, 64)), 256, 0, stream>>>(
      (const short*)abuf, (const short*)WT1, f_buf, al1, ar1, elbuf, er, N, C, C, 4, 3);
  aggr_fused_kernel<H_HEADS, D_HID><<<cdiv(N * 64, 256), 256, 0, stream>>>(
      row_ptr, csr_src, (const float4*)elbuf, er, f_buf, (unsigned int*)hbuf, bnbuf, N);
  bn_stats_kernel<<<256, C, 0, stream>>>((const unsigned short*)hbuf, bnsum, bnsq, N, C);
  bn_apply_kernel<<<cdiv(N * C, 256), 256, 0, stream>>>((const unsigned short*)hbuf, bnsum, bnsq,
                                                        g1, be1, abuf, elbuf, er, N, C);

  // ================= layer 2 (H=1, D=40, bias fused, direct to out) =========
  gemm_mfma<<<dim3(1, cdiv(N, 64)), 256, 0, stream>>>(
      (const short*)abuf, (const short*)WT2, f_buf, alp2, arp2, elbuf, er, N, C, F_OUT, 1, 1);
  aggr_out_kernel<<<cdiv(N * 64, 256), 256, 0, stream>>>(
      row_ptr, csr_src, elbuf, er, f_buf, b2, out, N);
}

// Round 12
// 702.419 us; speedup vs baseline: 1.3657x; 1.0425x over previous
//
#include <hip/hip_runtime.h>
#include <hip/hip_bf16.h>

typedef __hip_bfloat16 bf16;
typedef __attribute__((ext_vector_type(8))) short short8;
typedef __attribute__((ext_vector_type(4))) float f32x4;

static constexpr int N_NODES  = 50000;
static constexpr int N_EDGES  = 800000;
static constexpr int F_IN     = 128;
static constexpr int D_HID    = 128;
static constexpr int H_HEADS  = 3;
static constexpr int F_OUT    = 40;
static constexpr float BN_EPS = 1e-5f;
static constexpr float SLOPE  = 0.2f;

__device__ __forceinline__ float bfLo(unsigned int u) { return __uint_as_float(u << 16); }
__device__ __forceinline__ float bfHi(unsigned int u) { return __uint_as_float(u & 0xffff0000u); }
__device__ __forceinline__ float bfs(unsigned short s) { return __uint_as_float(((unsigned int)s) << 16); }
__device__ __forceinline__ unsigned int packbf(float a, float b) {
  union { bf16 h[2]; unsigned int u; } pk;
  pk.h[0] = __float2bfloat16(a);
  pk.h[1] = __float2bfloat16(b);
  return pk.u;
}

// ---------------- MFMA GEMM + fused el/er epilogue --------------------------
__global__ __launch_bounds__(256) void gemm_mfma(const short* __restrict__ A,
                                                 const short* __restrict__ WT,
                                                 bf16* __restrict__ C,
                                                 const float* __restrict__ alp,
                                                 const float* __restrict__ arp,
                                                 float* __restrict__ el,
                                                 float* __restrict__ er,
                                                 int M, int K, int Nc, int els, int ers) {
  constexpr int BM = 64, BN = 64, BK = 64, LDP = BK + 8;
  __shared__ short As[BM * LDP];
  __shared__ short Bs[BN * LDP];
  int tid = threadIdx.x;
  int wave = tid >> 6, lane = tid & 63;
  int bm = blockIdx.y, bn = blockIdx.x;
  int lrow = tid >> 3;
  int kcol = (tid & 7) * 8;

  int r0 = lrow, r1 = lrow + 32;
  int gr0 = bm * BM + r0; if (gr0 >= M) gr0 = M - 1;
  int gr1 = bm * BM + r1; if (gr1 >= M) gr1 = M - 1;
  const short* ga0 = A + (size_t)gr0 * K + kcol;
  const short* ga1 = A + (size_t)gr1 * K + kcol;
  const short* gb0 = WT + (size_t)(bn * BN + r0) * K + kcol;
  const short* gb1 = WT + (size_t)(bn * BN + r1) * K + kcol;
  short* la0 = &As[r0 * LDP + kcol];
  short* la1 = &As[r1 * LDP + kcol];
  short* lb0 = &Bs[r0 * LDP + kcol];
  short* lb1 = &Bs[r1 * LDP + kcol];

  f32x4 acc[4];
#pragma unroll
  for (int i = 0; i < 4; ++i) acc[i] = (f32x4){0.f, 0.f, 0.f, 0.f};

  int m15 = lane & 15;
  int ksub = (lane >> 4) * 8;
  const short* abase = &As[(wave * 16 + m15) * LDP + ksub];
  const short* bbase0 = &Bs[(0 * 16 + m15) * LDP + ksub];
  const short* bbase1 = &Bs[(1 * 16 + m15) * LDP + ksub];
  const short* bbase2 = &Bs[(2 * 16 + m15) * LDP + ksub];
  const short* bbase3 = &Bs[(3 * 16 + m15) * LDP + ksub];

  for (int k0 = 0; k0 < K; k0 += BK) {
    *(short8*)la0 = *(const short8*)ga0; ga0 += BK;
    *(short8*)la1 = *(const short8*)ga1; ga1 += BK;
    *(short8*)lb0 = *(const short8*)gb0; gb0 += BK;
    *(short8*)lb1 = *(const short8*)gb1; gb1 += BK;
    __syncthreads();
#pragma unroll
    for (int ks = 0; ks < BK; ks += 32) {
      short8 a = *(const short8*)(abase + ks);
      acc[0] = __builtin_amdgcn_mfma_f32_16x16x32_bf16(a, *(const short8*)(bbase0 + ks), acc[0], 0, 0, 0);
      acc[1] = __builtin_amdgcn_mfma_f32_16x16x32_bf16(a, *(const short8*)(bbase1 + ks), acc[1], 0, 0, 0);
      acc[2] = __builtin_amdgcn_mfma_f32_16x16x32_bf16(a, *(const short8*)(bbase2 + ks), acc[2], 0, 0, 0);
      acc[3] = __builtin_amdgcn_mfma_f32_16x16x32_bf16(a, *(const short8*)(bbase3 + ks), acc[3], 0, 0, 0);
    }
    __syncthreads();
  }

  int h = (bn * 64) >> 7;
  float alv[4], arv[4];
#pragma unroll
  for (int nb = 0; nb < 4; ++nb) {
    int col = bn * BN + nb * 16 + m15;
    alv[nb] = alp[col];
    arv[nb] = arp[col];
  }
#pragma unroll
  for (int r = 0; r < 4; ++r) {
    int row = bm * BM + wave * 16 + (lane >> 4) * 4 + r;
    float pe = 0.f, pr = 0.f;
#pragma unroll
    for (int nb = 0; nb < 4; ++nb) {
      float v = acc[nb][r];
      pe += v * alv[nb];
      pr += v * arv[nb];
      int col = bn * BN + nb * 16 + m15;
      if (row < M && col < Nc)
        C[(size_t)row * Nc + col] = __float2bfloat16(v);
    }
#pragma unroll
    for (int off = 1; off < 16; off <<= 1) {
      pe += __shfl_xor(pe, off);
      pr += __shfl_xor(pr, off);
    }
    if (m15 == 0 && row < M) {
      atomicAdd(&el[(size_t)row * els + h], pe);
      atomicAdd(&er[(size_t)row * ers + h], pr);
    }
  }
}

// ------------- prep: cast x, build WT0/1/2, pad al2/ar2, zero cnt/el/er -----
__global__ void prep_kernel(const float* __restrict__ x, bf16* __restrict__ abuf,
                            const float* __restrict__ W0, const float* __restrict__ W1,
                            const float* __restrict__ W2, bf16* __restrict__ WT0,
                            bf16* __restrict__ WT1, bf16* __restrict__ WT2,
                            const float* __restrict__ al2, const float* __restrict__ ar2,
                            float* __restrict__ alp2, float* __restrict__ arp2,
                            int* __restrict__ cnt, float* __restrict__ elbuf,
                            float* __restrict__ er) {
  const int NTOT = N_NODES * F_IN;  // 6.4M
  for (int i = blockIdx.x * blockDim.x + threadIdx.x; i < NTOT;
       i += gridDim.x * blockDim.x) {
    abuf[i] = __float2bfloat16(x[i]);
    if (i < 384 * 384) { int n = i / 384, k = i - n * 384; WT1[i] = __float2bfloat16(W1[(size_t)k * 384 + n]); }
    if (i < 384 * 128) { int n = i / 128, k = i - n * 128; WT0[i] = __float2bfloat16(W0[(size_t)k * 384 + n]); }
    if (i < 64 * 384)  { int n = i / 384, k = i - n * 384; WT2[i] = __float2bfloat16(n < F_OUT ? W2[(size_t)k * F_OUT + n] : 0.f); }
    if (i < 2 * N_NODES) cnt[i] = 0;
    if (i < 4 * N_NODES) elbuf[i] = 0.f;
    if (i < 3 * N_NODES) er[i] = 0.f;
    if (i < 64) { alp2[i] = i < F_OUT ? al2[i] : 0.f; arp2[i] = i < F_OUT ? ar2[i] : 0.f; }
  }
}

// ------------- CSR build ----------------------------------------------------
__global__ void hist_kernel(const int* __restrict__ dst, int* __restrict__ cnt, int E) {
  int i = blockIdx.x * blockDim.x + threadIdx.x;
  if (i < E) atomicAdd(cnt + dst[i], 1);
}

__global__ void scan_part_kernel(const int* __restrict__ cnt, int* __restrict__ blksum, int N) {
  __shared__ int sh[256];
  int i = blockIdx.x * 256 + threadIdx.x;
  sh[threadIdx.x] = (i < N) ? cnt[i] : 0;
  __syncthreads();
  for (int off = 128; off > 0; off >>= 1) {
    if (threadIdx.x < off) sh[threadIdx.x] += sh[threadIdx.x + off];
    __syncthreads();
  }
  if (threadIdx.x == 0) blksum[blockIdx.x] = sh[0];
}

__global__ void scan_top_kernel(const int* __restrict__ blksum, int* __restrict__ blkoff, int nblk) {
  __shared__ int sh[256];
  int t = threadIdx.x;
  int v = (t < nblk) ? blksum[t] : 0;
  sh[t] = v;
  __syncthreads();
  for (int off = 1; off < 256; off <<= 1) {
    int u = (t >= off) ? sh[t - off] : 0;
    __syncthreads();
    sh[t] += u;
    __syncthreads();
  }
  if (t < nblk) blkoff[t] = sh[t] - v;  // exclusive
}

__global__ void scan_write_kernel(const int* __restrict__ cnt, const int* __restrict__ blkoff,
                                  int* __restrict__ row_ptr, int N, int E) {
  __shared__ int sh[256];
  int i = blockIdx.x * 256 + threadIdx.x;
  int t = threadIdx.x;
  int v = (i < N) ? cnt[i] : 0;
  sh[t] = v;
  __syncthreads();
  for (int off = 1; off < 256; off <<= 1) {
    int u = (t >= off) ? sh[t - off] : 0;
    __syncthreads();
    sh[t] += u;
    __syncthreads();
  }
  if (i < N) row_ptr[i] = blkoff[blockIdx.x] + sh[t] - v;
  if (i == 0) row_ptr[N] = E;
}

__global__ void scatter_kernel(const int* __restrict__ src, const int* __restrict__ dst,
                               const int* __restrict__ row_ptr, int* __restrict__ fill,
                               int* __restrict__ csr_src, int E) {
  int i = blockIdx.x * blockDim.x + threadIdx.x;
  if (i < E) {
    int d = dst[i];
    int pos = row_ptr[d] + atomicAdd(fill + d, 1);
    csr_src[pos] = src[i];
  }
}

// ------------- fused aggregation: wave per dst, dwordx4 gather --------------
// Lanes 0..47 each read one uint4 (16B): 48*16B = 768B = full row per instr.
// Lane's 4 words lie in one head (lane>>4). Weights via LDS broadcast.
template <int H, int D>  // H=3, D=128 -> W=192 words, 48 uint4
__global__ __launch_bounds__(256) void aggr_fused_kernel(
    const int* __restrict__ row_ptr, const int* __restrict__ csr_src,
    const float4* __restrict__ el4, const float* __restrict__ er,
    const bf16* __restrict__ f, uint4* __restrict__ outq,
    float* __restrict__ bnzero, int N) {
  if (blockIdx.x == 0) {
    for (int j = threadIdx.x; j < 2 * H * D; j += 256) bnzero[j] = 0.f;
  }
  constexpr int W = H * D / 2;   // 192 words
  constexpr int WQ = W / 4;      // 48 uint4 per row
  __shared__ float wls[4][64 * H];
  int wv = threadIdx.x >> 6;
  int d = (blockIdx.x * 256 + threadIdx.x) >> 6;
  int lane = threadIdx.x & 63;
  if (d >= N) return;
  int beg = row_ptr[d], end = row_ptr[d + 1];
  const uint4* fq = (const uint4*)f;
  float* mywls = wls[wv];
  int hsel = lane >> 4;  // 0..2 for gather lanes (<48)

  float erd[H];
#pragma unroll
  for (int h = 0; h < H; ++h) erd[h] = er[d * H + h];
  float acc[8];
#pragma unroll
  for (int j = 0; j < 8; ++j) acc[j] = 0.f;
  float sp[H];
#pragma unroll
  for (int h = 0; h < H; ++h) sp[h] = 0.f;

  for (int k0 = beg; k0 < end; k0 += 64) {
    int nk = end - k0; if (nk > 64) nk = 64;
    int s_l = 0;
    if (lane < nk) {
      s_l = csr_src[k0 + lane];
      float4 e4 = el4[s_l];
      float ev[3] = {e4.x, e4.y, e4.z};
#pragma unroll
      for (int h = 0; h < H; ++h) {
        float sc = ev[h] + erd[h];
        sc = sc > 0.f ? sc : SLOPE * sc;
        float w = __expf(sc);
        mywls[lane * H + h] = w;
        sp[h] += w;
      }
    }
    for (int e = 0; e < nk; ++e) {
      int se = __shfl(s_l, e);
      if (lane < WQ) {
        float w = mywls[e * H + hsel];
        uint4 u = fq[(size_t)se * WQ + lane];
        acc[0] += w * bfLo(u.x); acc[1] += w * bfHi(u.x);
        acc[2] += w * bfLo(u.y); acc[3] += w * bfHi(u.y);
        acc[4] += w * bfLo(u.z); acc[5] += w * bfHi(u.z);
        acc[6] += w * bfLo(u.w); acc[7] += w * bfHi(u.w);
      }
    }
  }
#pragma unroll
  for (int h = 0; h < H; ++h) {
#pragma unroll
    for (int off = 32; off > 0; off >>= 1) sp[h] += __shfl_xor(sp[h], off);
  }
  if (lane < WQ) {
    float inv = 1.f / sp[hsel];
    uint4 r;
    r.x = packbf(acc[0] * inv, acc[1] * inv);
    r.y = packbf(acc[2] * inv, acc[3] * inv);
    r.z = packbf(acc[4] * inv, acc[5] * inv);
    r.w = packbf(acc[6] * inv, acc[7] * inv);
    outq[(size_t)d * WQ + lane] = r;
  }
}

// ------------- output-layer aggregation: H=1, D=40, bias fused --------------
__global__ __launch_bounds__(256) void aggr_out_kernel(
    const int* __restrict__ row_ptr, const int* __restrict__ csr_src,
    const float* __restrict__ el, const float* __restrict__ er,
    const bf16* __restrict__ f, const float* __restrict__ bias,
    float* __restrict__ out, int N) {
  constexpr int DW = F_OUT / 2;  // 20 words
  int d = (blockIdx.x * 256 + threadIdx.x) >> 6;
  int lane = threadIdx.x & 63;
  if (d >= N) return;
  int beg = row_ptr[d], end = row_ptr[d + 1];
  const unsigned int* fu = (const unsigned int*)f;
  float erd = er[d];
  float a0 = 0.f, a1 = 0.f, sp = 0.f;
  for (int k0 = beg; k0 < end; k0 += 64) {
    int nk = end - k0; if (nk > 64) nk = 64;
    int s_l = 0; float w_l = 0.f;
    if (lane < nk) {
      s_l = csr_src[k0 + lane];
      float sc = el[s_l] + erd;
      sc = sc > 0.f ? sc : SLOPE * sc;
      w_l = __expf(sc);
      sp += w_l;
    }
    for (int e = 0; e < nk; ++e) {
      int se = __shfl(s_l, e);
      float w = __shfl(w_l, e);
      if (lane < DW) {
        unsigned int u = fu[(size_t)se * DW + lane];
        a0 += w * bfLo(u);
        a1 += w * bfHi(u);
      }
    }
  }
#pragma unroll
  for (int off = 32; off > 0; off >>= 1) sp += __shfl_xor(sp, off);
  if (lane < DW) {
    float inv = 1.f / sp;
    *(float2*)&out[(size_t)d * F_OUT + 2 * lane] =
        make_float2(a0 * inv + bias[2 * lane], a1 * inv + bias[2 * lane + 1]);
  }
}

// ------------- BN stats (bf16 input, uint=2 channels per thread) ------------
__global__ void bn_stats_kernel(const unsigned int* __restrict__ h2, float* __restrict__ sum,
                                float* __restrict__ sumsq, int N, int C2) {
  int c = threadIdx.x;  // 0..C2-1 (192)
  float s0 = 0.f, q0 = 0.f, s1 = 0.f, q1 = 0.f;
  for (int n = blockIdx.x; n < N; n += gridDim.x) {
    unsigned int u = h2[(size_t)n * C2 + c];
    float v0 = bfLo(u), v1 = bfHi(u);
    s0 += v0; q0 += v0 * v0;
    s1 += v1; q1 += v1 * v1;
  }
  atomicAdd(sum + 2 * c, s0);
  atomicAdd(sum + 2 * c + 1, s1);
  atomicAdd(sumsq + 2 * c, q0);
  atomicAdd(sumsq + 2 * c + 1, q1);
}

// ------------- BN apply + ReLU (uint4 = 8 channels/thread) ------------------
__global__ void bn_apply_kernel(const uint4* __restrict__ h4, const float* __restrict__ sum,
                                const float* __restrict__ sumsq, const float* __restrict__ g,
                                const float* __restrict__ be, uint4* __restrict__ out4,
                                float* __restrict__ elz, float* __restrict__ erz,
                                int N, int C) {
  int idx = blockIdx.x * blockDim.x + threadIdx.x;
  if (idx < 4 * N) elz[idx] = 0.f;
  if (idx < 3 * N) erz[idx] = 0.f;
  int total = N * C / 8;
  if (idx >= total) return;
  int c0 = (idx * 8) % C;
  float inv_n = 1.f / (float)N;
  uint4 u = h4[idx];
  unsigned int uw[4] = {u.x, u.y, u.z, u.w};
  unsigned int rw[4];
#pragma unroll
  for (int k = 0; k < 4; ++k) {
    float o[2];
#pragma unroll
    for (int half = 0; half < 2; ++half) {
      int c = c0 + 2 * k + half;
      float v = half ? bfHi(uw[k]) : bfLo(uw[k]);
      float mu = sum[c] * inv_n;
      float var = sumsq[c] * inv_n - mu * mu;
      float val = (v - mu) * rsqrtf(var + BN_EPS) * g[c] + be[c];
      o[half] = val > 0.f ? val : 0.f;
    }
    rw[k] = packbf(o[0], o[1]);
  }
  uint4 r; r.x = rw[0]; r.y = rw[1]; r.z = rw[2]; r.w = rw[3];
  out4[idx] = r;
}

static inline int cdiv(int a, int b) { return (a + b - 1) / b; }

extern "C" void kernel_launch(void* const* d_in, const int* in_sizes, int n_in,
                              void* d_out, int out_size, void* d_ws, size_t ws_size,
                              hipStream_t stream) {
  const float* x   = (const float*)d_in[0];
  const int* src   = (const int*)d_in[1];
  const int* dst   = (const int*)d_in[2];
  const float* W0  = (const float*)d_in[3];
  const float* al0 = (const float*)d_in[4];
  const float* ar0 = (const float*)d_in[5];
  const float* W1  = (const float*)d_in[7];
  const float* al1 = (const float*)d_in[8];
  const float* ar1 = (const float*)d_in[9];
  const float* W2  = (const float*)d_in[11];
  const float* al2 = (const float*)d_in[12];
  const float* ar2 = (const float*)d_in[13];
  const float* b2  = (const float*)d_in[14];
  const float* g0  = (const float*)d_in[15];
  const float* be0 = (const float*)d_in[16];
  const float* g1  = (const float*)d_in[17];
  const float* be1 = (const float*)d_in[18];
  float* out = (float*)d_out;

  const int N = N_NODES, E = N_EDGES, H = H_HEADS;
  const int C = H * D_HID;  // 384
  const int nblk = cdiv(N, 256);  // 196

  // ---- workspace carve ----
  char* p = (char*)d_ws;
  auto take = [&](size_t bytes) {
    char* r = p;
    p += (bytes + 255) & ~(size_t)255;
    return r;
  };
  bf16*   f_buf   = (bf16*) take((size_t)N * C * sizeof(bf16));
  bf16*   hbuf    = (bf16*) take((size_t)N * C * sizeof(bf16));
  bf16*   abuf    = (bf16*) take((size_t)N * C * sizeof(bf16));
  float*  elbuf   = (float*)take((size_t)N * 4 * sizeof(float));
  float*  er      = (float*)take((size_t)N * H * sizeof(float));
  float*  bnbuf   = (float*)take((size_t)2 * C * sizeof(float));  // sum | sumsq
  bf16*   WT0     = (bf16*) take((size_t)C * F_IN * sizeof(bf16));
  bf16*   WT1     = (bf16*) take((size_t)C * C * sizeof(bf16));
  bf16*   WT2     = (bf16*) take((size_t)64 * C * sizeof(bf16));
  float*  alp2    = (float*)take(64 * sizeof(float));
  float*  arp2    = (float*)take(64 * sizeof(float));
  int*    cnt     = (int*)take((size_t)2 * N * sizeof(int));      // hist | fill
  int*    row_ptr = (int*)take((size_t)(N + 1) * sizeof(int));
  int*    csr_src = (int*)take((size_t)E * sizeof(int));
  int*    blksum  = (int*)take(256 * sizeof(int));
  int*    blkoff  = (int*)take(256 * sizeof(int));
  float*  bnsum = bnbuf, *bnsq = bnbuf + C;
  int*    fill  = cnt + N;

  // ---- prep + CSR build ----
  prep_kernel<<<cdiv(N * F_IN, 256), 256, 0, stream>>>(x, abuf, W0, W1, W2, WT0, WT1, WT2,
                                                       al2, ar2, alp2, arp2, cnt, elbuf, er);
  hist_kernel<<<cdiv(E, 256), 256, 0, stream>>>(dst, cnt, E);
  scan_part_kernel<<<nblk, 256, 0, stream>>>(cnt, blksum, N);
  scan_top_kernel<<<1, 256, 0, stream>>>(blksum, blkoff, nblk);
  scan_write_kernel<<<nblk, 256, 0, stream>>>(cnt, blkoff, row_ptr, N, E);
  scatter_kernel<<<cdiv(E, 256), 256, 0, stream>>>(src, dst, row_ptr, fill, csr_src, E);

  // ================= layer 0 =================
  gemm_mfma<<<dim3(C / 64, cdiv(N, 64)), 256, 0, stream>>>(
      (const short*)abuf, (const short*)WT0, f_buf, al0, ar0, elbuf, er, N, F_IN, C, 4, 3);
  aggr_fused_kernel<H_HEADS, D_HID><<<cdiv(N * 64, 256), 256, 0, stream>>>(
      row_ptr, csr_src, (const float4*)elbuf, er, f_buf, (uint4*)hbuf, bnbuf, N);
  bn_stats_kernel<<<256, C / 2, 0, stream>>>((const unsigned int*)hbuf, bnsum, bnsq, N, C / 2);
  bn_apply_kernel<<<cdiv(N * C / 8, 256), 256, 0, stream>>>(
      (const uint4*)hbuf, bnsum, bnsq, g0, be0, (uint4*)abuf, elbuf, er, N, C);

  // ================= layer 1 =================
  gemm_mfma<<<dim3(C / 64, cdiv(N, 64)), 256, 0, stream>>>(
      (const short*)abuf, (const short*)WT1, f_buf, al1, ar1, elbuf, er, N, C, C, 4, 3);
  aggr_fused_kernel<H_HEADS, D_HID><<<cdiv(N * 64, 256), 256, 0, stream>>>(
      row_ptr, csr_src, (const float4*)elbuf, er, f_buf, (uint4*)hbuf, bnbuf, N);
  bn_stats_kernel<<<256, C / 2, 0, stream>>>((const unsigned int*)hbuf, bnsum, bnsq, N, C / 2);
  bn_apply_kernel<<<cdiv(N * C / 8, 256), 256, 0, stream>>>(
      (const uint4*)hbuf, bnsum, bnsq, g1, be1, (uint4*)abuf, elbuf, er, N, C);

  // ================= layer 2 (H=1, D=40, bias fused, direct to out) =========
  gemm_mfma<<<dim3(1, cdiv(N, 64)), 256, 0, stream>>>(
      (const short*)abuf, (const short*)WT2, f_buf, alp2, arp2, elbuf, er, N, C, F_OUT, 1, 1);
  aggr_out_kernel<<<cdiv(N * 64, 256), 256, 0, stream>>>(
      row_ptr, csr_src, elbuf, er, f_buf, b2, out, N);
}

// Round 13
// 690.429 us; speedup vs baseline: 1.3894x; 1.0174x over previous
//
#include <hip/hip_runtime.h>
#include <hip/hip_bf16.h>

typedef __hip_bfloat16 bf16;
typedef __attribute__((ext_vector_type(8))) short short8;
typedef __attribute__((ext_vector_type(4))) float f32x4;

static constexpr int N_NODES  = 50000;
static constexpr int N_EDGES  = 800000;
static constexpr int F_IN     = 128;
static constexpr int D_HID    = 128;
static constexpr int H_HEADS  = 3;
static constexpr int F_OUT    = 40;
static constexpr float BN_EPS = 1e-5f;
static constexpr float SLOPE  = 0.2f;

__device__ __forceinline__ float bfLo(unsigned int u) { return __uint_as_float(u << 16); }
__device__ __forceinline__ float bfHi(unsigned int u) { return __uint_as_float(u & 0xffff0000u); }
__device__ __forceinline__ unsigned int packbf(float a, float b) {
  union { bf16 h[2]; unsigned int u; } pk;
  pk.h[0] = __float2bfloat16(a);
  pk.h[1] = __float2bfloat16(b);
  return pk.u;
}

// ---------------- MFMA GEMM + fused el/er epilogue --------------------------
__global__ __launch_bounds__(256) void gemm_mfma(const short* __restrict__ A,
                                                 const short* __restrict__ WT,
                                                 bf16* __restrict__ C,
                                                 const float* __restrict__ alp,
                                                 const float* __restrict__ arp,
                                                 float* __restrict__ el,
                                                 float* __restrict__ er,
                                                 int M, int K, int Nc, int els, int ers) {
  constexpr int BM = 64, BN = 64, BK = 64, LDP = BK + 8;
  __shared__ short As[BM * LDP];
  __shared__ short Bs[BN * LDP];
  int tid = threadIdx.x;
  int wave = tid >> 6, lane = tid & 63;
  int bm = blockIdx.y, bn = blockIdx.x;
  int lrow = tid >> 3;
  int kcol = (tid & 7) * 8;

  int r0 = lrow, r1 = lrow + 32;
  int gr0 = bm * BM + r0; if (gr0 >= M) gr0 = M - 1;
  int gr1 = bm * BM + r1; if (gr1 >= M) gr1 = M - 1;
  const short* ga0 = A + (size_t)gr0 * K + kcol;
  const short* ga1 = A + (size_t)gr1 * K + kcol;
  const short* gb0 = WT + (size_t)(bn * BN + r0) * K + kcol;
  const short* gb1 = WT + (size_t)(bn * BN + r1) * K + kcol;
  short* la0 = &As[r0 * LDP + kcol];
  short* la1 = &As[r1 * LDP + kcol];
  short* lb0 = &Bs[r0 * LDP + kcol];
  short* lb1 = &Bs[r1 * LDP + kcol];

  f32x4 acc[4];
#pragma unroll
  for (int i = 0; i < 4; ++i) acc[i] = (f32x4){0.f, 0.f, 0.f, 0.f};

  int m15 = lane & 15;
  int ksub = (lane >> 4) * 8;
  const short* abase = &As[(wave * 16 + m15) * LDP + ksub];
  const short* bbase0 = &Bs[(0 * 16 + m15) * LDP + ksub];
  const short* bbase1 = &Bs[(1 * 16 + m15) * LDP + ksub];
  const short* bbase2 = &Bs[(2 * 16 + m15) * LDP + ksub];
  const short* bbase3 = &Bs[(3 * 16 + m15) * LDP + ksub];

  for (int k0 = 0; k0 < K; k0 += BK) {
    *(short8*)la0 = *(const short8*)ga0; ga0 += BK;
    *(short8*)la1 = *(const short8*)ga1; ga1 += BK;
    *(short8*)lb0 = *(const short8*)gb0; gb0 += BK;
    *(short8*)lb1 = *(const short8*)gb1; gb1 += BK;
    __syncthreads();
#pragma unroll
    for (int ks = 0; ks < BK; ks += 32) {
      short8 a = *(const short8*)(abase + ks);
      acc[0] = __builtin_amdgcn_mfma_f32_16x16x32_bf16(a, *(const short8*)(bbase0 + ks), acc[0], 0, 0, 0);
      acc[1] = __builtin_amdgcn_mfma_f32_16x16x32_bf16(a, *(const short8*)(bbase1 + ks), acc[1], 0, 0, 0);
      acc[2] = __builtin_amdgcn_mfma_f32_16x16x32_bf16(a, *(const short8*)(bbase2 + ks), acc[2], 0, 0, 0);
      acc[3] = __builtin_amdgcn_mfma_f32_16x16x32_bf16(a, *(const short8*)(bbase3 + ks), acc[3], 0, 0, 0);
    }
    __syncthreads();
  }

  int h = (bn * 64) >> 7;
  float alv[4], arv[4];
#pragma unroll
  for (int nb = 0; nb < 4; ++nb) {
    int col = bn * BN + nb * 16 + m15;
    alv[nb] = alp[col];
    arv[nb] = arp[col];
  }
#pragma unroll
  for (int r = 0; r < 4; ++r) {
    int row = bm * BM + wave * 16 + (lane >> 4) * 4 + r;
    float pe = 0.f, pr = 0.f;
#pragma unroll
    for (int nb = 0; nb < 4; ++nb) {
      float v = acc[nb][r];
      pe += v * alv[nb];
      pr += v * arv[nb];
      int col = bn * BN + nb * 16 + m15;
      if (row < M && col < Nc)
        C[(size_t)row * Nc + col] = __float2bfloat16(v);
    }
#pragma unroll
    for (int off = 1; off < 16; off <<= 1) {
      pe += __shfl_xor(pe, off);
      pr += __shfl_xor(pr, off);
    }
    if (m15 == 0 && row < M) {
      atomicAdd(&el[(size_t)row * els + h], pe);
      atomicAdd(&er[(size_t)row * ers + h], pr);
    }
  }
}

// ------------- prep: cast x, build WT0/1/2, pad al2/ar2, zero cnt/el/er -----
__global__ void prep_kernel(const float* __restrict__ x, bf16* __restrict__ abuf,
                            const float* __restrict__ W0, const float* __restrict__ W1,
                            const float* __restrict__ W2, bf16* __restrict__ WT0,
                            bf16* __restrict__ WT1, bf16* __restrict__ WT2,
                            const float* __restrict__ al2, const float* __restrict__ ar2,
                            float* __restrict__ alp2, float* __restrict__ arp2,
                            int* __restrict__ cnt, float* __restrict__ elbuf,
                            float* __restrict__ er) {
  const int NTOT = N_NODES * F_IN;  // 6.4M
  for (int i = blockIdx.x * blockDim.x + threadIdx.x; i < NTOT;
       i += gridDim.x * blockDim.x) {
    abuf[i] = __float2bfloat16(x[i]);
    if (i < 384 * 384) { int n = i / 384, k = i - n * 384; WT1[i] = __float2bfloat16(W1[(size_t)k * 384 + n]); }
    if (i < 384 * 128) { int n = i / 128, k = i - n * 128; WT0[i] = __float2bfloat16(W0[(size_t)k * 384 + n]); }
    if (i < 64 * 384)  { int n = i / 384, k = i - n * 384; WT2[i] = __float2bfloat16(n < F_OUT ? W2[(size_t)k * F_OUT + n] : 0.f); }
    if (i < 2 * N_NODES) cnt[i] = 0;
    if (i < 4 * N_NODES) elbuf[i] = 0.f;
    if (i < 3 * N_NODES) er[i] = 0.f;
    if (i < 64) { alp2[i] = i < F_OUT ? al2[i] : 0.f; arp2[i] = i < F_OUT ? ar2[i] : 0.f; }
  }
}

// ------------- CSR build ----------------------------------------------------
__global__ void hist_kernel(const int* __restrict__ dst, int* __restrict__ cnt, int E) {
  int i = blockIdx.x * blockDim.x + threadIdx.x;
  if (i < E) atomicAdd(cnt + dst[i], 1);
}

__global__ void scan_part_kernel(const int* __restrict__ cnt, int* __restrict__ blksum, int N) {
  __shared__ int sh[256];
  int i = blockIdx.x * 256 + threadIdx.x;
  sh[threadIdx.x] = (i < N) ? cnt[i] : 0;
  __syncthreads();
  for (int off = 128; off > 0; off >>= 1) {
    if (threadIdx.x < off) sh[threadIdx.x] += sh[threadIdx.x + off];
    __syncthreads();
  }
  if (threadIdx.x == 0) blksum[blockIdx.x] = sh[0];
}

__global__ void scan_top_kernel(const int* __restrict__ blksum, int* __restrict__ blkoff, int nblk) {
  __shared__ int sh[256];
  int t = threadIdx.x;
  int v = (t < nblk) ? blksum[t] : 0;
  sh[t] = v;
  __syncthreads();
  for (int off = 1; off < 256; off <<= 1) {
    int u = (t >= off) ? sh[t - off] : 0;
    __syncthreads();
    sh[t] += u;
    __syncthreads();
  }
  if (t < nblk) blkoff[t] = sh[t] - v;  // exclusive
}

__global__ void scan_write_kernel(const int* __restrict__ cnt, const int* __restrict__ blkoff,
                                  int* __restrict__ row_ptr, int N, int E) {
  __shared__ int sh[256];
  int i = blockIdx.x * 256 + threadIdx.x;
  int t = threadIdx.x;
  int v = (i < N) ? cnt[i] : 0;
  sh[t] = v;
  __syncthreads();
  for (int off = 1; off < 256; off <<= 1) {
    int u = (t >= off) ? sh[t - off] : 0;
    __syncthreads();
    sh[t] += u;
    __syncthreads();
  }
  if (i < N) row_ptr[i] = blkoff[blockIdx.x] + sh[t] - v;
  if (i == 0) row_ptr[N] = E;
}

__global__ void scatter_kernel(const int* __restrict__ src, const int* __restrict__ dst,
                               const int* __restrict__ row_ptr, int* __restrict__ fill,
                               int* __restrict__ csr_src, int E) {
  int i = blockIdx.x * blockDim.x + threadIdx.x;
  if (i < E) {
    int d = dst[i];
    int pos = row_ptr[d] + atomicAdd(fill + d, 1);
    csr_src[pos] = src[i];
  }
}

// ------------- fused aggregation: wave/dst, LDS (s,w) stage, MLP-4 gather ---
template <int H, int D>  // H=3, D=128 -> 192 words, 48 uint4
__global__ __launch_bounds__(256) void aggr_fused_kernel(
    const int* __restrict__ row_ptr, const int* __restrict__ csr_src,
    const float4* __restrict__ el4, const float* __restrict__ er,
    const bf16* __restrict__ f, uint4* __restrict__ outq,
    float* __restrict__ bnzero, int N) {
  if (blockIdx.x == 0) {
    for (int j = threadIdx.x; j < 2 * H * D; j += 256) bnzero[j] = 0.f;
  }
  constexpr int W = H * D / 2;   // 192 words
  constexpr int WQ = W / 4;      // 48 uint4 per row
  __shared__ float wls[4][64 * H];
  __shared__ int   sls[4][64];
  int wv = threadIdx.x >> 6;
  int d = (blockIdx.x * 256 + threadIdx.x) >> 6;
  int lane = threadIdx.x & 63;
  if (d >= N) return;
  int beg = row_ptr[d], end = row_ptr[d + 1];
  const uint4* fq = (const uint4*)f;
  float* mywls = wls[wv];
  int* mysls = sls[wv];
  int hsel = lane >> 4;  // 0..2 for gather lanes (<48)

  float erd[H];
#pragma unroll
  for (int h = 0; h < H; ++h) erd[h] = er[d * H + h];
  float acc[8];
#pragma unroll
  for (int j = 0; j < 8; ++j) acc[j] = 0.f;
  float sp[H];
#pragma unroll
  for (int h = 0; h < H; ++h) sp[h] = 0.f;

  for (int k0 = beg; k0 < end; k0 += 64) {
    int nk = end - k0; if (nk > 64) nk = 64;
    if (lane < nk) {
      int s_l = csr_src[k0 + lane];
      mysls[lane] = s_l;
      float4 e4 = el4[s_l];
      float ev[3] = {e4.x, e4.y, e4.z};
#pragma unroll
      for (int h = 0; h < H; ++h) {
        float sc = ev[h] + erd[h];
        sc = sc > 0.f ? sc : SLOPE * sc;
        float w = __expf(sc);
        mywls[lane * H + h] = w;
        sp[h] += w;
      }
    }
    int e = 0;
    for (; e + 4 <= nk; e += 4) {
      int se0 = mysls[e], se1 = mysls[e + 1], se2 = mysls[e + 2], se3 = mysls[e + 3];
      if (lane < WQ) {
        float w0 = mywls[(e + 0) * H + hsel];
        float w1 = mywls[(e + 1) * H + hsel];
        float w2 = mywls[(e + 2) * H + hsel];
        float w3 = mywls[(e + 3) * H + hsel];
        uint4 u0 = fq[(size_t)se0 * WQ + lane];
        uint4 u1 = fq[(size_t)se1 * WQ + lane];
        uint4 u2 = fq[(size_t)se2 * WQ + lane];
        uint4 u3 = fq[(size_t)se3 * WQ + lane];
        acc[0] += w0 * bfLo(u0.x); acc[1] += w0 * bfHi(u0.x);
        acc[2] += w0 * bfLo(u0.y); acc[3] += w0 * bfHi(u0.y);
        acc[4] += w0 * bfLo(u0.z); acc[5] += w0 * bfHi(u0.z);
        acc[6] += w0 * bfLo(u0.w); acc[7] += w0 * bfHi(u0.w);
        acc[0] += w1 * bfLo(u1.x); acc[1] += w1 * bfHi(u1.x);
        acc[2] += w1 * bfLo(u1.y); acc[3] += w1 * bfHi(u1.y);
        acc[4] += w1 * bfLo(u1.z); acc[5] += w1 * bfHi(u1.z);
        acc[6] += w1 * bfLo(u1.w); acc[7] += w1 * bfHi(u1.w);
        acc[0] += w2 * bfLo(u2.x); acc[1] += w2 * bfHi(u2.x);
        acc[2] += w2 * bfLo(u2.y); acc[3] += w2 * bfHi(u2.y);
        acc[4] += w2 * bfLo(u2.z); acc[5] += w2 * bfHi(u2.z);
        acc[6] += w2 * bfLo(u2.w); acc[7] += w2 * bfHi(u2.w);
        acc[0] += w3 * bfLo(u3.x); acc[1] += w3 * bfHi(u3.x);
        acc[2] += w3 * bfLo(u3.y); acc[3] += w3 * bfHi(u3.y);
        acc[4] += w3 * bfLo(u3.z); acc[5] += w3 * bfHi(u3.z);
        acc[6] += w3 * bfLo(u3.w); acc[7] += w3 * bfHi(u3.w);
      }
    }
    for (; e < nk; ++e) {
      int se = mysls[e];
      if (lane < WQ) {
        float w = mywls[e * H + hsel];
        uint4 u = fq[(size_t)se * WQ + lane];
        acc[0] += w * bfLo(u.x); acc[1] += w * bfHi(u.x);
        acc[2] += w * bfLo(u.y); acc[3] += w * bfHi(u.y);
        acc[4] += w * bfLo(u.z); acc[5] += w * bfHi(u.z);
        acc[6] += w * bfLo(u.w); acc[7] += w * bfHi(u.w);
      }
    }
  }
#pragma unroll
  for (int h = 0; h < H; ++h) {
#pragma unroll
    for (int off = 32; off > 0; off >>= 1) sp[h] += __shfl_xor(sp[h], off);
  }
  if (lane < WQ) {
    float inv = 1.f / sp[hsel];
    uint4 r;
    r.x = packbf(acc[0] * inv, acc[1] * inv);
    r.y = packbf(acc[2] * inv, acc[3] * inv);
    r.z = packbf(acc[4] * inv, acc[5] * inv);
    r.w = packbf(acc[6] * inv, acc[7] * inv);
    outq[(size_t)d * WQ + lane] = r;
  }
}

// ------------- output-layer aggregation: H=1, D=40, bias fused, MLP-4 -------
__global__ __launch_bounds__(256) void aggr_out_kernel(
    const int* __restrict__ row_ptr, const int* __restrict__ csr_src,
    const float* __restrict__ el, const float* __restrict__ er,
    const bf16* __restrict__ f, const float* __restrict__ bias,
    float* __restrict__ out, int N) {
  constexpr int DW = F_OUT / 2;  // 20 words
  __shared__ float wls[4][64];
  __shared__ int   sls[4][64];
  int wv = threadIdx.x >> 6;
  int d = (blockIdx.x * 256 + threadIdx.x) >> 6;
  int lane = threadIdx.x & 63;
  if (d >= N) return;
  int beg = row_ptr[d], end = row_ptr[d + 1];
  const unsigned int* fu = (const unsigned int*)f;
  float* mywls = wls[wv];
  int* mysls = sls[wv];
  float erd = er[d];
  float a0 = 0.f, a1 = 0.f, sp = 0.f;
  for (int k0 = beg; k0 < end; k0 += 64) {
    int nk = end - k0; if (nk > 64) nk = 64;
    if (lane < nk) {
      int s_l = csr_src[k0 + lane];
      mysls[lane] = s_l;
      float sc = el[s_l] + erd;
      sc = sc > 0.f ? sc : SLOPE * sc;
      float w = __expf(sc);
      mywls[lane] = w;
      sp += w;
    }
    int e = 0;
    for (; e + 4 <= nk; e += 4) {
      int se0 = mysls[e], se1 = mysls[e + 1], se2 = mysls[e + 2], se3 = mysls[e + 3];
      if (lane < DW) {
        float w0 = mywls[e], w1 = mywls[e + 1], w2 = mywls[e + 2], w3 = mywls[e + 3];
        unsigned int u0 = fu[(size_t)se0 * DW + lane];
        unsigned int u1 = fu[(size_t)se1 * DW + lane];
        unsigned int u2 = fu[(size_t)se2 * DW + lane];
        unsigned int u3 = fu[(size_t)se3 * DW + lane];
        a0 += w0 * bfLo(u0); a1 += w0 * bfHi(u0);
        a0 += w1 * bfLo(u1); a1 += w1 * bfHi(u1);
        a0 += w2 * bfLo(u2); a1 += w2 * bfHi(u2);
        a0 += w3 * bfLo(u3); a1 += w3 * bfHi(u3);
      }
    }
    for (; e < nk; ++e) {
      int se = mysls[e];
      if (lane < DW) {
        float w = mywls[e];
        unsigned int u = fu[(size_t)se * DW + lane];
        a0 += w * bfLo(u); a1 += w * bfHi(u);
      }
    }
  }
#pragma unroll
  for (int off = 32; off > 0; off >>= 1) sp += __shfl_xor(sp, off);
  if (lane < DW) {
    float inv = 1.f / sp;
    *(float2*)&out[(size_t)d * F_OUT + 2 * lane] =
        make_float2(a0 * inv + bias[2 * lane], a1 * inv + bias[2 * lane + 1]);
  }
}

// ------------- BN stats (bf16 input, uint=2 channels per thread) ------------
__global__ void bn_stats_kernel(const unsigned int* __restrict__ h2, float* __restrict__ sum,
                                float* __restrict__ sumsq, int N, int C2) {
  int c = threadIdx.x;  // 0..C2-1 (192)
  float s0 = 0.f, q0 = 0.f, s1 = 0.f, q1 = 0.f;
  for (int n = blockIdx.x; n < N; n += gridDim.x) {
    unsigned int u = h2[(size_t)n * C2 + c];
    float v0 = bfLo(u), v1 = bfHi(u);
    s0 += v0; q0 += v0 * v0;
    s1 += v1; q1 += v1 * v1;
  }
  atomicAdd(sum + 2 * c, s0);
  atomicAdd(sum + 2 * c + 1, s1);
  atomicAdd(sumsq + 2 * c, q0);
  atomicAdd(sumsq + 2 * c + 1, q1);
}

// ------------- BN apply + ReLU (uint4 = 8 channels/thread) ------------------
__global__ void bn_apply_kernel(const uint4* __restrict__ h4, const float* __restrict__ sum,
                                const float* __restrict__ sumsq, const float* __restrict__ g,
                                const float* __restrict__ be, uint4* __restrict__ out4,
                                float* __restrict__ elz, float* __restrict__ erz,
                                int N, int C) {
  int idx = blockIdx.x * blockDim.x + threadIdx.x;
  if (idx < 4 * N) elz[idx] = 0.f;
  if (idx < 3 * N) erz[idx] = 0.f;
  int total = N * C / 8;
  if (idx >= total) return;
  int c0 = (idx * 8) % C;
  float inv_n = 1.f / (float)N;
  uint4 u = h4[idx];
  unsigned int uw[4] = {u.x, u.y, u.z, u.w};
  unsigned int rw[4];
#pragma unroll
  for (int k = 0; k < 4; ++k) {
    float o[2];
#pragma unroll
    for (int half = 0; half < 2; ++half) {
      int c = c0 + 2 * k + half;
      float v = half ? bfHi(uw[k]) : bfLo(uw[k]);
      float mu = sum[c] * inv_n;
      float var = sumsq[c] * inv_n - mu * mu;
      float val = (v - mu) * rsqrtf(var + BN_EPS) * g[c] + be[c];
      o[half] = val > 0.f ? val : 0.f;
    }
    rw[k] = packbf(o[0], o[1]);
  }
  uint4 r; r.x = rw[0]; r.y = rw[1]; r.z = rw[2]; r.w = rw[3];
  out4[idx] = r;
}

static inline int cdiv(int a, int b) { return (a + b - 1) / b; }

extern "C" void kernel_launch(void* const* d_in, const int* in_sizes, int n_in,
                              void* d_out, int out_size, void* d_ws, size_t ws_size,
                              hipStream_t stream) {
  const float* x   = (const float*)d_in[0];
  const int* src   = (const int*)d_in[1];
  const int* dst   = (const int*)d_in[2];
  const float* W0  = (const float*)d_in[3];
  const float* al0 = (const float*)d_in[4];
  const float* ar0 = (const float*)d_in[5];
  const float* W1  = (const float*)d_in[7];
  const float* al1 = (const float*)d_in[8];
  const float* ar1 = (const float*)d_in[9];
  const float* W2  = (const float*)d_in[11];
  const float* al2 = (const float*)d_in[12];
  const float* ar2 = (const float*)d_in[13];
  const float* b2  = (const float*)d_in[14];
  const float* g0  = (const float*)d_in[15];
  const float* be0 = (const float*)d_in[16];
  const float* g1  = (const float*)d_in[17];
  const float* be1 = (const float*)d_in[18];
  float* out = (float*)d_out;

  const int N = N_NODES, E = N_EDGES, H = H_HEADS;
  const int C = H * D_HID;  // 384
  const int nblk = cdiv(N, 256);  // 196

  // ---- workspace carve ----
  char* p = (char*)d_ws;
  auto take = [&](size_t bytes) {
    char* r = p;
    p += (bytes + 255) & ~(size_t)255;
    return r;
  };
  bf16*   f_buf   = (bf16*) take((size_t)N * C * sizeof(bf16));
  bf16*   hbuf    = (bf16*) take((size_t)N * C * sizeof(bf16));
  bf16*   abuf    = (bf16*) take((size_t)N * C * sizeof(bf16));
  float*  elbuf   = (float*)take((size_t)N * 4 * sizeof(float));
  float*  er      = (float*)take((size_t)N * H * sizeof(float));
  float*  bnbuf   = (float*)take((size_t)2 * C * sizeof(float));  // sum | sumsq
  bf16*   WT0     = (bf16*) take((size_t)C * F_IN * sizeof(bf16));
  bf16*   WT1     = (bf16*) take((size_t)C * C * sizeof(bf16));
  bf16*   WT2     = (bf16*) take((size_t)64 * C * sizeof(bf16));
  float*  alp2    = (float*)take(64 * sizeof(float));
  float*  arp2    = (float*)take(64 * sizeof(float));
  int*    cnt     = (int*)take((size_t)2 * N * sizeof(int));      // hist | fill
  int*    row_ptr = (int*)take((size_t)(N + 1) * sizeof(int));
  int*    csr_src = (int*)take((size_t)E * sizeof(int));
  int*    blksum  = (int*)take(256 * sizeof(int));
  int*    blkoff  = (int*)take(256 * sizeof(int));
  float*  bnsum = bnbuf, *bnsq = bnbuf + C;
  int*    fill  = cnt + N;

  // ---- prep + CSR build ----
  prep_kernel<<<cdiv(N * F_IN, 256), 256, 0, stream>>>(x, abuf, W0, W1, W2, WT0, WT1, WT2,
                                                       al2, ar2, alp2, arp2, cnt, elbuf, er);
  hist_kernel<<<cdiv(E, 256), 256, 0, stream>>>(dst, cnt, E);
  scan_part_kernel<<<nblk, 256, 0, stream>>>(cnt, blksum, N);
  scan_top_kernel<<<1, 256, 0, stream>>>(blksum, blkoff, nblk);
  scan_write_kernel<<<nblk, 256, 0, stream>>>(cnt, blkoff, row_ptr, N, E);
  scatter_kernel<<<cdiv(E, 256), 256, 0, stream>>>(src, dst, row_ptr, fill, csr_src, E);

  // ================= layer 0 =================
  gemm_mfma<<<dim3(C / 64, cdiv(N, 64)), 256, 0, stream>>>(
      (const short*)abuf, (const short*)WT0, f_buf, al0, ar0, elbuf, er, N, F_IN, C, 4, 3);
  aggr_fused_kernel<H_HEADS, D_HID><<<cdiv(N * 64, 256), 256, 0, stream>>>(
      row_ptr, csr_src, (const float4*)elbuf, er, f_buf, (uint4*)hbuf, bnbuf, N);
  bn_stats_kernel<<<256, C / 2, 0, stream>>>((const unsigned int*)hbuf, bnsum, bnsq, N, C / 2);
  bn_apply_kernel<<<cdiv(N * C / 8, 256), 256, 0, stream>>>(
      (const uint4*)hbuf, bnsum, bnsq, g0, be0, (uint4*)abuf, elbuf, er, N, C);

  // ================= layer 1 =================
  gemm_mfma<<<dim3(C / 64, cdiv(N, 64)), 256, 0, stream>>>(
      (const short*)abuf, (const short*)WT1, f_buf, al1, ar1, elbuf, er, N, C, C, 4, 3);
  aggr_fused_kernel<H_HEADS, D_HID><<<cdiv(N * 64, 256), 256, 0, stream>>>(
      row_ptr, csr_src, (const float4*)elbuf, er, f_buf, (uint4*)hbuf, bnbuf, N);
  bn_stats_kernel<<<256, C / 2, 0, stream>>>((const unsigned int*)hbuf, bnsum, bnsq, N, C / 2);
  bn_apply_kernel<<<cdiv(N * C / 8, 256), 256, 0, stream>>>(
      (const uint4*)hbuf, bnsum, bnsq, g1, be1, (uint4*)abuf, elbuf, er, N, C);

  // ================= layer 2 (H=1, D=40, bias fused, direct to out) =========
  gemm_mfma<<<dim3(1, cdiv(N, 64)), 256, 0, stream>>>(
      (const short*)abuf, (const short*)WT2, f_buf, alp2, arp2, elbuf, er, N, C, F_OUT, 1, 1);
  aggr_out_kernel<<<cdiv(N * 64, 256), 256, 0, stream>>>(
      row_ptr, csr_src, elbuf, er, f_buf, b2, out, N);
}